// Round 7
// baseline (299.809 us; speedup 1.0000x reference)
//
#include <hip/hip_runtime.h>
#include <math.h>

#define BB 64
#define NN 1024
#define DD 768
#define KK 8

// ws layout (floats):
//   [0, 6144)             s_norm (K x D)
//   [6144, 6144+524288)   logits [b][k][n]  (B*K*N)
//   [530432, 530496)      per-b partial ortho sums (64)
#define WS_SNORM   0
#define WS_LOGITS  6144
#define WS_PART    (6144 + 524288)

// out layout (floats):
//   [0, 393216)           slots_b  (B*K*D)
//   [393216]              ortho_loss
//   [393217, 458753)      img_space_mask (B*N)

// DPP butterfly add: x += x_from(lane permuted by CTRL). VALU-only (no DS pipe).
// 0xB1 = quad_perm [1,0,3,2] (xor1), 0x4E = quad_perm [2,3,0,1] (xor2),
// 0x128 = row_ror:8 (== xor8 within a 16-lane row).
template <int CTRL>
__device__ __forceinline__ float dpp_add(float x) {
    const int xi = __float_as_int(x);
    const int yi = __builtin_amdgcn_update_dpp(0, xi, CTRL, 0xF, 0xF, true);
    return x + __int_as_float(yi);
}

__device__ __forceinline__ float dot12(const float4& a0, const float4& a1, const float4& a2,
                                       const float4& b0, const float4& b1, const float4& b2) {
    float r = 0.f;
    r = fmaf(a0.x, b0.x, r); r = fmaf(a0.y, b0.y, r);
    r = fmaf(a0.z, b0.z, r); r = fmaf(a0.w, b0.w, r);
    r = fmaf(a1.x, b1.x, r); r = fmaf(a1.y, b1.y, r);
    r = fmaf(a1.z, b1.z, r); r = fmaf(a1.w, b1.w, r);
    r = fmaf(a2.x, b2.x, r); r = fmaf(a2.y, b2.y, r);
    r = fmaf(a2.z, b2.z, r); r = fmaf(a2.w, b2.w, r);
    return r;
}

// Reduction identical (bit-for-bit math) to the round-4 hardware-validated one:
//   fold xor4 (split by b2) -> fold xor16 (b4) -> fold xor32 (b5),
//   then DPP xor1/xor2/xor8. Lane holds k = 4*b2+2*b4+b5; store (lane&11)==0.
__device__ __forceinline__ void reduce_store(float (&acc)[KK], float u, int n,
                                             int lane, int b2, int b4, int b5,
                                             int b, float* __restrict__ logits) {
    float w[4];
#pragma unroll
    for (int j = 0; j < 4; ++j) {
        const float send = b2 ? acc[j] : acc[j + 4];
        const float keep = b2 ? acc[j + 4] : acc[j];
        w[j] = keep + __shfl_xor(send, 4, 64);
    }
    u += __shfl_xor(u, 4, 64);

    const float s0 = b4 ? w[0] : w[2];
    const float s1 = b4 ? w[1] : w[3];
    const float y0 = (b4 ? w[2] : w[0]) + __shfl_xor(s0, 16, 64);
    const float y1 = (b4 ? w[3] : w[1]) + __shfl_xor(s1, 16, 64);
    u += __shfl_xor(u, 16, 64);

    const float sz = b5 ? y0 : y1;
    float z = (b5 ? y1 : y0) + __shfl_xor(sz, 32, 64);
    u += __shfl_xor(u, 32, 64);

    z = dpp_add<0xB1>(z);   u = dpp_add<0xB1>(u);
    z = dpp_add<0x4E>(z);   u = dpp_add<0x4E>(u);
    z = dpp_add<0x128>(z);  u = dpp_add<0x128>(u);

    const float rn = 1.0f / fmaxf(sqrtf(u), 1e-6f);
    if ((lane & 11) == 0) {                    // b0=b1=b3=0: 8 lanes, all k
        const int k = 4 * b2 + 2 * b4 + b5;
        logits[(((b << 3) + k) << 10) + n] = z * rn;
    }
}

// ---------------------------------------------------------------- kernel 1
// broadcast raw slots -> out[0..393215] as float4.
// K*D = 6144 floats = 1536 float4 per b (NOT a power of two -> div/mod).
__global__ void k_broadcast(const float* __restrict__ slots, float* __restrict__ out) {
    const int b   = blockIdx.x / 6;
    const int r   = blockIdx.x % 6;
    const int idx = r * 256 + threadIdx.x;                 // 0..1535 (float4)
    reinterpret_cast<float4*>(out)[b * 1536 + idx] =
        reinterpret_cast<const float4*>(slots)[idx];
}

// ---------------------------------------------------------------- kernel 1b
// normalize slots -> ws snorm. grid 8 x 256
__global__ void k_snorm(const float* __restrict__ slots, float* __restrict__ snorm) {
    const int k = blockIdx.x;
    const int t = threadIdx.x;
    const int lane = t & 63, wave = t >> 6;
    __shared__ float wsum[4];
    float s = 0.f;
    for (int j = t; j < DD; j += 256) {
        float v = slots[k * DD + j];
        s += v * v;
    }
#pragma unroll
    for (int off = 1; off < 64; off <<= 1) s += __shfl_xor(s, off, 64);
    if (lane == 0) wsum[wave] = s;
    __syncthreads();
    const float tot = wsum[0] + wsum[1] + wsum[2] + wsum[3];
    const float rn = 1.0f / fmaxf(sqrtf(tot), 1e-6f);
    for (int j = t; j < DD; j += 256) snorm[k * DD + j] = slots[k * DD + j] * rn;
}

// ---------------------------------------------------------------- kernel 2
// logits[b][k][n] = dot(x[b,n,:], snorm[k,:]) / max(||x_n||, eps)
// grid 1024 x 256; b = blk>>4, chunk = blk&15; wave owns 16 consecutive n.
// v3: slots in LDS (24 KB, conflict-free b128: consecutive lanes read
// consecutive 16B) instead of 96 VGPRs -> ~100 VGPR -> ~5 waves/SIMD.
// Two patches per iteration amortize each slot read over 2 dots
// (12 ds_read_b128 per patch) and double outstanding global loads.
__launch_bounds__(256)
__global__ void k_logits(const float* __restrict__ x, const float* __restrict__ snorm,
                         float* __restrict__ logits) {
    const int b     = blockIdx.x >> 4;
    const int chunk = blockIdx.x & 15;
    const int wave  = threadIdx.x >> 6;
    const int lane  = threadIdx.x & 63;
    const int b2 = (lane >> 2) & 1, b4 = (lane >> 4) & 1, b5 = (lane >> 5) & 1;

    // stage normalized slots: sl[k*192 + j*64 + lane] = snorm[k*768 + j*256 + lane*4 ..+3]
    __shared__ float4 sl[KK * 192];            // 24 KB
    for (int i = threadIdx.x; i < KK * 192; i += 256)
        sl[i] = reinterpret_cast<const float4*>(snorm)[i];
    __syncthreads();

    const int n_base = chunk * 64 + wave * 16;
    const float4* xrow = reinterpret_cast<const float4*>(x + (long)(b * NN + n_base) * DD);

    auto compute_pair = [&](int n, const float4& a0, const float4& a1, const float4& a2,
                                   const float4& e0, const float4& e1, const float4& e2) {
        float accA[KK], accB[KK];
#pragma unroll
        for (int k = 0; k < KK; ++k) {
            const float4 s0 = sl[k * 192 + lane];
            const float4 s1 = sl[k * 192 + 64 + lane];
            const float4 s2 = sl[k * 192 + 128 + lane];
            accA[k] = dot12(a0, a1, a2, s0, s1, s2);
            accB[k] = dot12(e0, e1, e2, s0, s1, s2);
        }
        const float uA = dot12(a0, a1, a2, a0, a1, a2);
        const float uB = dot12(e0, e1, e2, e0, e1, e2);
        reduce_store(accA, uA, n,     lane, b2, b4, b5, b, logits);
        reduce_store(accB, uB, n + 1, lane, b2, b4, b5, b, logits);
    };

    // software pipeline over 8 patch-pairs; every body iteration prefetches
    // the next pair (6 float4 in flight), last pair peeled.
    float4 a0 = xrow[lane],        a1 = xrow[64 + lane],  a2 = xrow[128 + lane];
    float4 e0 = xrow[192 + lane],  e1 = xrow[256 + lane], e2 = xrow[320 + lane];

    for (int i = 0; i < 7; ++i) {
        const float4* xq = xrow + (2 * i + 2) * 192;     // next pair (patch stride 192 f4)
        float4 pA0 = xq[lane],        pA1 = xq[64 + lane],  pA2 = xq[128 + lane];
        float4 pB0 = xq[192 + lane],  pB1 = xq[256 + lane], pB2 = xq[320 + lane];
        compute_pair(n_base + 2 * i, a0, a1, a2, e0, e1, e2);
        a0 = pA0; a1 = pA1; a2 = pA2; e0 = pB0; e1 = pB1; e2 = pB2;
    }
    compute_pair(n_base + 14, a0, a1, a2, e0, e1, e2);
}

// ---------------------------------------------------------------- kernel 3
// per-b: top-8 thresholds, img_space_mask, exp rows, gram, ortho partial.
// grid 64 x 512 (8 waves; wave w owns row w).
__launch_bounds__(512)
__global__ void k_select(const float* __restrict__ logits, float* __restrict__ out_mask,
                         float* __restrict__ partials) {
    const int b = blockIdx.x;
    __shared__ float lds[KK][1032];   // padded rows (stride 1032 -> bank spread)
    __shared__ float thr[KK], rmax[KK], rsum[KK];
    __shared__ float gpart[8][64];
    const int t = threadIdx.x, lane = t & 63, wave = t >> 6;

    // A: load logits[b] (8 x 1024) into LDS
    for (int f = t; f < KK * NN; f += 512) lds[f >> 10][f & 1023] = logits[b * (KK * NN) + f];
    __syncthreads();

    // B: top-8 per row via 8x argmax-extract; wave w handles row w.
    {
        const int k = wave;
        float v[16];
#pragma unroll
        for (int i = 0; i < 16; ++i) v[i] = lds[k][i * 64 + lane];
        float th = 0.f, mx = -1e30f;
        for (int e = 0; e < 8; ++e) {
            float lv = -1e30f; int li = 0;
#pragma unroll
            for (int i = 0; i < 16; ++i) {
                if (v[i] > lv) { lv = v[i]; li = i * 64 + lane; }
            }
#pragma unroll
            for (int off = 1; off < 64; off <<= 1) {
                const float ov = __shfl_xor(lv, off, 64);
                const int   oi = __shfl_xor(li, off, 64);
                if (ov > lv || (ov == lv && oi < li)) { lv = ov; li = oi; }
            }
            if (e == 0) mx = lv;
            th = lv;
            // remove exactly the found instance (static indices only)
#pragma unroll
            for (int i = 0; i < 16; ++i)
                if (i * 64 + lane == li) v[i] = -1e30f;
        }
        if (lane == 0) { thr[k] = th; rmax[k] = mx; }
    }
    __syncthreads();

    // M: img_space_mask[b][n] = any_k(logit >= thr)
    for (int n = t; n < NN; n += 512) {
        float m = 0.f;
#pragma unroll
        for (int k = 0; k < KK; ++k) m = fmaxf(m, (lds[k][n] >= thr[k]) ? 1.f : 0.f);
        out_mask[b * NN + n] = m;
    }
    __syncthreads();

    // C: overwrite rows with exp(logit - rowmax) for selected, 0 otherwise; row sums.
    {
        const int k = wave;
        const float th = thr[k], mx = rmax[k];
        float s = 0.f;
#pragma unroll
        for (int i = 0; i < 16; ++i) {
            const int n = i * 64 + lane;
            const float lg = lds[k][n];
            const float p = (lg >= th) ? __expf(lg - mx) : 0.f;
            lds[k][n] = p;
            s += p;
        }
#pragma unroll
        for (int off = 1; off < 64; off <<= 1) s += __shfl_xor(s, off, 64);
        if (lane == 0) rsum[k] = s;
    }
    __syncthreads();

    // D: gram[k][j] = (sum_n p_k p_j) / (rsum_k rsum_j); partial ortho sum.
    {
        const int k = lane >> 3, j = lane & 7;
        float s = 0.f;
#pragma unroll 8
        for (int i = 0; i < 128; ++i) {
            const int n = (wave << 7) + i;
            s += lds[k][n] * lds[j][n];
        }
        gpart[wave][lane] = s;
    }
    __syncthreads();
    if (wave == 0) {
        const int k = lane >> 3, j = lane & 7;
        float g = 0.f;
#pragma unroll
        for (int w = 0; w < 8; ++w) g += gpart[w][lane];
        g *= (1.0f / rsum[k]) * (1.0f / rsum[j]);
        float d = fabsf(g - ((k == j) ? 1.f : 0.f));
#pragma unroll
        for (int off = 1; off < 64; off <<= 1) d += __shfl_xor(d, off, 64);
        if (lane == 0) partials[b] = d;
    }
}

// ---------------------------------------------------------------- kernel 4
__global__ void k_final(const float* __restrict__ partials, float* __restrict__ out_loss) {
    const int lane = threadIdx.x;  // 64
    float v = partials[lane];
#pragma unroll
    for (int off = 1; off < 64; off <<= 1) v += __shfl_xor(v, off, 64);
    if (lane == 0) out_loss[0] = v * (1.0f / 4096.0f);
}

extern "C" void kernel_launch(void* const* d_in, const int* in_sizes, int n_in,
                              void* d_out, int out_size, void* d_ws, size_t ws_size,
                              hipStream_t stream) {
    const float* x     = (const float*)d_in[0];   // (64,1024,768) f32
    const float* slots = (const float*)d_in[1];   // (1,8,768)     f32
    float* out = (float*)d_out;
    float* ws  = (float*)d_ws;

    float* snorm    = ws + WS_SNORM;
    float* logits   = ws + WS_LOGITS;
    float* partials = ws + WS_PART;

    float* out_slots = out;                         // 393216
    float* out_loss  = out + 393216;                // 1
    float* out_mask  = out + 393217;                // 65536

    k_broadcast<<<dim3(384),     dim3(256), 0, stream>>>(slots, out_slots);
    k_snorm    <<<dim3(KK),      dim3(256), 0, stream>>>(slots, snorm);
    k_logits   <<<dim3(BB * 16), dim3(256), 0, stream>>>(x, snorm, logits);
    k_select   <<<dim3(BB),      dim3(512), 0, stream>>>(logits, out_mask, partials);
    k_final    <<<dim3(1),       dim3(64),  0, stream>>>(partials, out_loss);
}